// Round 4
// baseline (1790.113 us; speedup 1.0000x reference)
//
#include <hip/hip_runtime.h>
#include <hip/hip_bf16.h>

typedef __attribute__((ext_vector_type(8))) short short8;
typedef __attribute__((ext_vector_type(4))) float floatx4;

static __device__ __forceinline__ short bf16bits(float f) {
    __hip_bfloat16 h = __float2bfloat16(f);
    return __builtin_bit_cast(short, h);
}

// ---------------------------------------------------------------------------
// Runtime input-dtype detector. Reads 64 words of w_qkv (~N(0,1)*0.02, never
// zero). bf16 data: low half-word exponent field in [96,127] ~always.
// fp32 data: low half-word is uniform mantissa bits -> in-range ~12%.
// flag = 1 means inputs are fp32.  (Round 2->3 behavior confirmed fp32.)
// ---------------------------------------------------------------------------
__global__ void detect_dtype(const unsigned* __restrict__ probe, int* __restrict__ flag) {
    int lane = threadIdx.x;
    unsigned w = probe[lane];
    int e = (w >> 7) & 0xFF;              // exponent field of the LOW half-word as bf16
    bool bf16ish = (e >= 96) && (e <= 127);
    unsigned long long m = __ballot(bf16ish);
    if (lane == 0) *flag = (__popcll(m) < 48) ? 1 : 0;
}

// ---------------------------------------------------------------------------
// GEMM: C[M,N] = A[M,K] * W[N,K]^T, fp32 accumulate, CT output (bf16 or f32).
// A/W may be fp32 or bf16 in global (runtime flag; converted to bf16 during
// LDS staging). A_DUAL=false pins A to bf16 (our own intermediates).
// 128x128 tile, BK=64, 4 waves x (64x64), mfma 16x16x32. LDS rows padded
// to 72 elems.
// ---------------------------------------------------------------------------
template<bool A_DUAL, typename CT>
__global__ __launch_bounds__(256) void gemm_bt(
    const void* __restrict__ A,
    const void* __restrict__ W,
    CT* __restrict__ C,
    const int* __restrict__ flagp,
    int M, int N, int K)
{
    __shared__ alignas(16) short lA[128 * 72];
    __shared__ alignas(16) short lB[128 * 72];

    const bool f32 = (*flagp != 0);

    const int tid  = threadIdx.x;
    const int wave = tid >> 6;
    const int lane = tid & 63;
    const int quad = lane >> 4;
    const int l16  = lane & 15;

    const int m0 = blockIdx.x * 128;
    const int n0 = blockIdx.y * 128;
    const int wm = (wave & 1) * 64;
    const int wn = (wave >> 1) * 64;

    floatx4 acc[4][4];
#pragma unroll
    for (int i = 0; i < 4; i++)
#pragma unroll
        for (int j = 0; j < 4; j++) acc[i][j] = (floatx4)0.0f;

    const short* Ab = (const short*)A;
    const short* Wb = (const short*)W;
    const float* Af = (const float*)A;
    const float* Wf = (const float*)W;

    for (int k0 = 0; k0 < K; k0 += 64) {
        __syncthreads();
#pragma unroll
        for (int i = 0; i < 4; i++) {
            int chunk = tid + i * 256;      // 1024 chunks = 128 rows x 8
            int row = chunk >> 3;
            int cc  = chunk & 7;
            // ---- A ----
            if (A_DUAL && f32) {
                const float* src = Af + (size_t)(m0 + row) * K + k0 + cc * 8;
                floatx4 f0 = *(const floatx4*)(src);
                floatx4 f1 = *(const floatx4*)(src + 4);
                short8 s;
#pragma unroll
                for (int j = 0; j < 4; j++) { s[j] = bf16bits(f0[j]); s[j + 4] = bf16bits(f1[j]); }
                *(short8*)(&lA[row * 72 + cc * 8]) = s;
            } else {
                *(short8*)(&lA[row * 72 + cc * 8]) =
                    *(const short8*)(Ab + (size_t)(m0 + row) * K + k0 + cc * 8);
            }
            // ---- W ----
            if (f32) {
                const float* src = Wf + (size_t)(n0 + row) * K + k0 + cc * 8;
                floatx4 f0 = *(const floatx4*)(src);
                floatx4 f1 = *(const floatx4*)(src + 4);
                short8 s;
#pragma unroll
                for (int j = 0; j < 4; j++) { s[j] = bf16bits(f0[j]); s[j + 4] = bf16bits(f1[j]); }
                *(short8*)(&lB[row * 72 + cc * 8]) = s;
            } else {
                *(short8*)(&lB[row * 72 + cc * 8]) =
                    *(const short8*)(Wb + (size_t)(n0 + row) * K + k0 + cc * 8);
            }
        }
        __syncthreads();
#pragma unroll
        for (int kk = 0; kk < 64; kk += 32) {
            short8 af[4], bf[4];
#pragma unroll
            for (int i = 0; i < 4; i++)
                af[i] = *(const short8*)(&lA[(wm + i * 16 + l16) * 72 + kk + quad * 8]);
#pragma unroll
            for (int j = 0; j < 4; j++)
                bf[j] = *(const short8*)(&lB[(wn + j * 16 + l16) * 72 + kk + quad * 8]);
#pragma unroll
            for (int i = 0; i < 4; i++)
#pragma unroll
                for (int j = 0; j < 4; j++)
                    acc[i][j] = __builtin_amdgcn_mfma_f32_16x16x32_bf16(
                        af[i], bf[j], acc[i][j], 0, 0, 0);
        }
    }

    // C/D layout: col = lane&15, row = quad*4 + reg  (verified gfx950 mapping)
#pragma unroll
    for (int i = 0; i < 4; i++) {
#pragma unroll
        for (int j = 0; j < 4; j++) {
            int gm = m0 + wm + i * 16 + quad * 4;
            int gn = n0 + wn + j * 16 + l16;
#pragma unroll
            for (int r = 0; r < 4; r++) {
                float v = acc[i][j][r];
                if constexpr (sizeof(CT) == 2)
                    C[(size_t)(gm + r) * N + gn] = (CT)__float2bfloat16(v);
                else
                    C[(size_t)(gm + r) * N + gn] = (CT)v;
            }
        }
    }
}

// ---------------------------------------------------------------------------
// RoPE + RMSNorm, in place on bf16 qkv. cos/sin/qw/kw may be fp32 or bf16
// (runtime flag). One wave per (token, head-slot): slots 0..31 q, 32..39 k.
// Lane d holds dims d and d+64 (rotate_half pairing).
// ---------------------------------------------------------------------------
__global__ __launch_bounds__(256) void rope_norm(
    __hip_bfloat16* __restrict__ qkv,
    const void* __restrict__ cosb,
    const void* __restrict__ sinb,
    const void* __restrict__ qw,
    const void* __restrict__ kw,
    const int* __restrict__ flagp)
{
    const bool f32 = (*flagp != 0);
    int wid  = blockIdx.x * 4 + (threadIdx.x >> 6);
    int lane = threadIdx.x & 63;
    int token = wid / 40;
    int idx   = wid % 40;
    int s = token & 2047;                 // position within sequence (S=2048)

    int off;
    const void* w;
    if (idx < 32) { off = (idx >> 2) * 768 + (idx & 3) * 128; w = qw; }
    else          { off = (idx - 32) * 768 + 512;             w = kw; }

    auto rd = [&](const void* p, int i) -> float {
        return f32 ? ((const float*)p)[i]
                   : __bfloat162float(((const __hip_bfloat16*)p)[i]);
    };

    __hip_bfloat16* p = qkv + (size_t)token * 6144 + off;
    int d = lane;
    float x1 = __bfloat162float(p[d]);
    float x2 = __bfloat162float(p[d + 64]);
    float c1 = rd(cosb, s * 128 + d);
    float c2 = rd(cosb, s * 128 + d + 64);
    float s1 = rd(sinb, s * 128 + d);
    float s2 = rd(sinb, s * 128 + d + 64);
    float y1 = x1 * c1 - x2 * s1;         // rope: first half
    float y2 = x2 * c2 + x1 * s2;         // rope: second half

    float ss = y1 * y1 + y2 * y2;
#pragma unroll
    for (int m = 1; m < 64; m <<= 1) ss += __shfl_xor(ss, m, 64);
    float r = rsqrtf(ss * (1.0f / 128.0f) + 1e-5f);

    p[d]      = __float2bfloat16(y1 * r * rd(w, d));
    p[d + 64] = __float2bfloat16(y2 * r * rd(w, d + 64));
}

// ---------------------------------------------------------------------------
// Flash attention (full softmax, GQA), all-bf16 qkv intermediate.
// Block = (b, h, 64 q-rows), 4 waves x 16 q-rows. K staged (stride 136),
// V staged (stride 137, scalar b-frag gathers), P round-trips per-wave LDS.
// ---------------------------------------------------------------------------
__global__ __launch_bounds__(256) void attn_kernel(
    const __hip_bfloat16* __restrict__ qkv,
    __hip_bfloat16* __restrict__ attn_out)
{
    __shared__ alignas(16) short lK[64 * 136];
    __shared__ alignas(16) short lV[64 * 137];
    __shared__ alignas(16) short lP[4][16 * 72];

    const int bid  = blockIdx.x;            // 2048 = b(2) * h(32) * qt(32)
    const int qt   = bid & 31;
    const int h    = (bid >> 5) & 31;
    const int b    = bid >> 10;
    const int kvh  = h >> 2;
    const int wave = threadIdx.x >> 6;
    const int lane = threadIdx.x & 63;
    const int quad = lane >> 4;
    const int l16  = lane & 15;

    const size_t qoff = (size_t)kvh * 768 + (size_t)(h & 3) * 128;
    const size_t koff = (size_t)kvh * 768 + 512;
    const size_t voff = koff + 128;
    const short* qkvs = (const short*)qkv;

    // Q fragments: A-layout m=l16, k = kk*32 + quad*8 + j
    const int qrow = qt * 64 + wave * 16 + l16;
    const size_t qtok = (size_t)(b * 2048 + qrow);
    short8 qf[4];
#pragma unroll
    for (int kk = 0; kk < 4; kk++)
        qf[kk] = *(const short8*)(qkvs + qtok * 6144 + qoff + kk * 32 + quad * 8);

    floatx4 o[8];
#pragma unroll
    for (int n = 0; n < 8; n++) o[n] = (floatx4)0.0f;
    float mrow[4], lrow[4];
#pragma unroll
    for (int r = 0; r < 4; r++) { mrow[r] = -3.0e4f; lrow[r] = 0.0f; }

    const float scale = 0.08838834764831845f;  // 1/sqrt(128)

    for (int kt = 0; kt < 32; kt++) {
        __syncthreads();
        // stage K,V tile (64 keys x 128 dims)
#pragma unroll
        for (int i = 0; i < 4; i++) {
            int chunk = threadIdx.x + i * 256;   // 1024 = 64 keys x 16 chunks
            int key = chunk >> 4;
            int dc  = chunk & 15;
            size_t tok = (size_t)(b * 2048 + kt * 64 + key);
            short8 k8 = *(const short8*)(qkvs + tok * 6144 + koff + dc * 8);
            *(short8*)(&lK[key * 136 + dc * 8]) = k8;
            short8 v8 = *(const short8*)(qkvs + tok * 6144 + voff + dc * 8);
#pragma unroll
            for (int j = 0; j < 8; j++) lV[key * 137 + dc * 8 + j] = v8[j];
        }
        __syncthreads();

        // S = Q K^T  (16 q-rows x 64 keys)
        floatx4 sc[4];
#pragma unroll
        for (int n = 0; n < 4; n++) sc[n] = (floatx4)0.0f;
#pragma unroll
        for (int kk = 0; kk < 4; kk++) {
#pragma unroll
            for (int n = 0; n < 4; n++) {
                short8 bfr = *(const short8*)(&lK[(n * 16 + l16) * 136 + kk * 32 + quad * 8]);
                sc[n] = __builtin_amdgcn_mfma_f32_16x16x32_bf16(qf[kk], bfr, sc[n], 0, 0, 0);
            }
        }

        // online softmax; row r of this quad = quad*4 + r; reduce over l16 bits
        float mnew[4], alpha[4];
#pragma unroll
        for (int r = 0; r < 4; r++) {
            float mx = fmaxf(fmaxf(sc[0][r], sc[1][r]), fmaxf(sc[2][r], sc[3][r])) * scale;
#pragma unroll
            for (int m = 1; m < 16; m <<= 1) mx = fmaxf(mx, __shfl_xor(mx, m, 64));
            float mn = fmaxf(mrow[r], mx);
            alpha[r] = __expf(mrow[r] - mn);
            mnew[r]  = mn;
        }
#pragma unroll
        for (int n = 0; n < 4; n++) {
#pragma unroll
            for (int r = 0; r < 4; r++) {
                float p = __expf(sc[n][r] * scale - mnew[r]);
                sc[n][r] = p;
                lP[wave][(quad * 4 + r) * 72 + n * 16 + l16] = bf16bits(p);
            }
        }
#pragma unroll
        for (int r = 0; r < 4; r++) {
            float sm = sc[0][r] + sc[1][r] + sc[2][r] + sc[3][r];
#pragma unroll
            for (int m = 1; m < 16; m <<= 1) sm += __shfl_xor(sm, m, 64);
            lrow[r] = lrow[r] * alpha[r] + sm;
            mrow[r] = mnew[r];
        }
#pragma unroll
        for (int n = 0; n < 8; n++)
#pragma unroll
            for (int r = 0; r < 4; r++) o[n][r] *= alpha[r];

        // fence lP scalar-stores -> short8 loads
        __syncthreads();

        // O += P * V
#pragma unroll
        for (int kk2 = 0; kk2 < 2; kk2++) {
            short8 pf = *(const short8*)(&lP[wave][l16 * 72 + kk2 * 32 + quad * 8]);
#pragma unroll
            for (int n = 0; n < 8; n++) {
                short8 vf;
#pragma unroll
                for (int j = 0; j < 8; j++)
                    vf[j] = lV[(kk2 * 32 + quad * 8 + j) * 137 + n * 16 + l16];
                o[n] = __builtin_amdgcn_mfma_f32_16x16x32_bf16(pf, vf, o[n], 0, 0, 0);
            }
        }
    }

    // epilogue: out[token][h*128 + d] / softmax denom
#pragma unroll
    for (int n = 0; n < 8; n++) {
#pragma unroll
        for (int r = 0; r < 4; r++) {
            int row = qt * 64 + wave * 16 + quad * 4 + r;
            size_t tok = (size_t)(b * 2048 + row);
            float v = o[n][r] / lrow[r];
            attn_out[tok * 4096 + h * 128 + n * 16 + l16] = __float2bfloat16(v);
        }
    }
}

// ---------------------------------------------------------------------------
extern "C" void kernel_launch(void* const* d_in, const int* in_sizes, int n_in,
                              void* d_out, int out_size, void* d_ws, size_t ws_size,
                              hipStream_t stream) {
    const void* hidden = d_in[0];
    const void* cosb   = d_in[1];
    const void* sinb   = d_in[2];
    const void* w_qkv  = d_in[3];
    const void* w_o    = d_in[4];
    const void* qw     = d_in[5];
    const void* kw     = d_in[6];

    __hip_bfloat16* qkv    = (__hip_bfloat16*)d_ws;                       // 4096 x 6144
    __hip_bfloat16* attn_o = (__hip_bfloat16*)((char*)d_ws +
                              (size_t)4096 * 6144 * 2);                   // 4096 x 4096
    float* outp            = (float*)d_out;                               // fp32 output

    // flag #1 lives in d_out[0..3] (d_out fully overwritten by final GEMM)
    int* flag1 = (int*)d_out;
    // flag #2 lives in qkv[0..3] (qkv is dead after attn_kernel)
    int* flag2 = (int*)qkv;

    detect_dtype<<<1, 64, 0, stream>>>((const unsigned*)w_qkv, flag1);

    dim3 g1(32, 48);  // 4096/128 x 6144/128
    gemm_bt<true, __hip_bfloat16><<<g1, 256, 0, stream>>>(hidden, w_qkv, qkv, flag1, 4096, 6144, 4096);

    rope_norm<<<40960, 256, 0, stream>>>(qkv, cosb, sinb, qw, kw, flag1);

    attn_kernel<<<2048, 256, 0, stream>>>(qkv, attn_o);

    detect_dtype<<<1, 64, 0, stream>>>((const unsigned*)w_qkv, flag2);

    dim3 g2(32, 32);  // 4096/128 x 4096/128
    gemm_bt<false, float><<<g2, 256, 0, stream>>>(attn_o, w_o, outp, flag2, 4096, 4096, 4096);
}

// Round 5
// 1282.431 us; speedup vs baseline: 1.3959x; 1.3959x over previous
//
#include <hip/hip_runtime.h>
#include <hip/hip_bf16.h>

typedef __attribute__((ext_vector_type(8))) short short8;
typedef __attribute__((ext_vector_type(4))) float floatx4;

static __device__ __forceinline__ short bf16bits(float f) {
    __hip_bfloat16 h = __float2bfloat16(f);
    return __builtin_bit_cast(short, h);
}

#define GLDS(g, l) __builtin_amdgcn_global_load_lds( \
    (const __attribute__((address_space(1))) void*)(g), \
    (__attribute__((address_space(3))) void*)(l), 16, 0, 0)

// ---------------------------------------------------------------------------
// fp32 -> bf16 bulk convert. Thread i handles 8 elems.
// ---------------------------------------------------------------------------
__global__ __launch_bounds__(256) void cvt_bf16(
    const float* __restrict__ src, __hip_bfloat16* __restrict__ dst)
{
    size_t i = ((size_t)blockIdx.x * 256 + threadIdx.x) * 8;
    floatx4 f0 = *(const floatx4*)(src + i);
    floatx4 f1 = *(const floatx4*)(src + i + 4);
    short8 s;
#pragma unroll
    for (int j = 0; j < 4; j++) { s[j] = bf16bits(f0[j]); s[j + 4] = bf16bits(f1[j]); }
    *(short8*)((short*)dst + i) = s;
}

// ---------------------------------------------------------------------------
// FAST GEMM (m97 structure): C[M,N] = A[M,K] * W[N,K]^T, bf16 in, fp32 acc.
// 128x128 tile, BK=64, unpadded LDS, global_load_lds dwordx4 staging.
// ---------------------------------------------------------------------------
template<typename CT>
__global__ __launch_bounds__(256) void gemm_bt_fast(
    const __hip_bfloat16* __restrict__ A,
    const __hip_bfloat16* __restrict__ W,
    CT* __restrict__ C, int M, int N, int K)
{
    __shared__ alignas(16) short lA[128 * 64];
    __shared__ alignas(16) short lB[128 * 64];

    const int tid  = threadIdx.x;
    const int wave = tid >> 6;
    const int lane = tid & 63;
    const int quad = lane >> 4;
    const int l16  = lane & 15;

    const int m0 = blockIdx.x * 128;
    const int n0 = blockIdx.y * 128;
    const int wm = (wave & 1) * 64;
    const int wn = (wave >> 1) * 64;

    const int srow = lane >> 3;        // 0..7  (row within 8-row chunk)
    const int scol = (lane & 7) * 8;   // elem col (16B per lane)

    const short* Ag = (const short*)A;
    const short* Wg = (const short*)W;

    floatx4 acc[4][4];
#pragma unroll
    for (int i = 0; i < 4; i++)
#pragma unroll
        for (int j = 0; j < 4; j++) acc[i][j] = (floatx4)0.0f;

    for (int k0 = 0; k0 < K; k0 += 64) {
        __syncthreads();
#pragma unroll
        for (int i = 0; i < 4; i++) {
            int c   = wave * 4 + i;            // chunk id 0..15 (8 rows x 1KB)
            int row = c * 8 + srow;
            GLDS(Ag + (size_t)(m0 + row) * K + k0 + scol, &lA[c * 512]);
            GLDS(Wg + (size_t)(n0 + row) * K + k0 + scol, &lB[c * 512]);
        }
        __syncthreads();
#pragma unroll
        for (int kk = 0; kk < 64; kk += 32) {
            short8 af[4], bf[4];
#pragma unroll
            for (int i = 0; i < 4; i++)
                af[i] = *(const short8*)(&lA[(wm + i * 16 + l16) * 64 + kk + quad * 8]);
#pragma unroll
            for (int j = 0; j < 4; j++)
                bf[j] = *(const short8*)(&lB[(wn + j * 16 + l16) * 64 + kk + quad * 8]);
#pragma unroll
            for (int i = 0; i < 4; i++)
#pragma unroll
                for (int j = 0; j < 4; j++)
                    acc[i][j] = __builtin_amdgcn_mfma_f32_16x16x32_bf16(
                        af[i], bf[j], acc[i][j], 0, 0, 0);
        }
    }
#pragma unroll
    for (int i = 0; i < 4; i++)
#pragma unroll
        for (int j = 0; j < 4; j++) {
            int gm = m0 + wm + i * 16 + quad * 4;
            int gn = n0 + wn + j * 16 + l16;
#pragma unroll
            for (int r = 0; r < 4; r++) {
                float v = acc[i][j][r];
                if constexpr (sizeof(CT) == 2)
                    C[(size_t)(gm + r) * N + gn] = (CT)__float2bfloat16(v);
                else
                    C[(size_t)(gm + r) * N + gn] = (CT)v;
            }
        }
}

// ---------------------------------------------------------------------------
// FALLBACK GEMM (round-4 proven): fp32 or bf16 A, fp32 W, convert in staging.
// Used only if ws_size can't hold the bf16 weight copies.
// ---------------------------------------------------------------------------
template<bool AF32, typename CT>
__global__ __launch_bounds__(256) void gemm_bt_slow(
    const void* __restrict__ A,
    const float* __restrict__ Wf,
    CT* __restrict__ C, int M, int N, int K)
{
    __shared__ alignas(16) short lA[128 * 72];
    __shared__ alignas(16) short lB[128 * 72];

    const int tid  = threadIdx.x;
    const int wave = tid >> 6;
    const int lane = tid & 63;
    const int quad = lane >> 4;
    const int l16  = lane & 15;

    const int m0 = blockIdx.x * 128;
    const int n0 = blockIdx.y * 128;
    const int wm = (wave & 1) * 64;
    const int wn = (wave >> 1) * 64;

    floatx4 acc[4][4];
#pragma unroll
    for (int i = 0; i < 4; i++)
#pragma unroll
        for (int j = 0; j < 4; j++) acc[i][j] = (floatx4)0.0f;

    const short* Ab = (const short*)A;
    const float* Af = (const float*)A;

    for (int k0 = 0; k0 < K; k0 += 64) {
        __syncthreads();
#pragma unroll
        for (int i = 0; i < 4; i++) {
            int chunk = tid + i * 256;
            int row = chunk >> 3;
            int cc  = chunk & 7;
            if (AF32) {
                const float* src = Af + (size_t)(m0 + row) * K + k0 + cc * 8;
                floatx4 f0 = *(const floatx4*)(src);
                floatx4 f1 = *(const floatx4*)(src + 4);
                short8 s;
#pragma unroll
                for (int j = 0; j < 4; j++) { s[j] = bf16bits(f0[j]); s[j + 4] = bf16bits(f1[j]); }
                *(short8*)(&lA[row * 72 + cc * 8]) = s;
            } else {
                *(short8*)(&lA[row * 72 + cc * 8]) =
                    *(const short8*)(Ab + (size_t)(m0 + row) * K + k0 + cc * 8);
            }
            const float* src = Wf + (size_t)(n0 + row) * K + k0 + cc * 8;
            floatx4 f0 = *(const floatx4*)(src);
            floatx4 f1 = *(const floatx4*)(src + 4);
            short8 s;
#pragma unroll
            for (int j = 0; j < 4; j++) { s[j] = bf16bits(f0[j]); s[j + 4] = bf16bits(f1[j]); }
            *(short8*)(&lB[row * 72 + cc * 8]) = s;
        }
        __syncthreads();
#pragma unroll
        for (int kk = 0; kk < 64; kk += 32) {
            short8 af[4], bf[4];
#pragma unroll
            for (int i = 0; i < 4; i++)
                af[i] = *(const short8*)(&lA[(wm + i * 16 + l16) * 72 + kk + quad * 8]);
#pragma unroll
            for (int j = 0; j < 4; j++)
                bf[j] = *(const short8*)(&lB[(wn + j * 16 + l16) * 72 + kk + quad * 8]);
#pragma unroll
            for (int i = 0; i < 4; i++)
#pragma unroll
                for (int j = 0; j < 4; j++)
                    acc[i][j] = __builtin_amdgcn_mfma_f32_16x16x32_bf16(
                        af[i], bf[j], acc[i][j], 0, 0, 0);
        }
    }
#pragma unroll
    for (int i = 0; i < 4; i++)
#pragma unroll
        for (int j = 0; j < 4; j++) {
            int gm = m0 + wm + i * 16 + quad * 4;
            int gn = n0 + wn + j * 16 + l16;
#pragma unroll
            for (int r = 0; r < 4; r++) {
                float v = acc[i][j][r];
                if constexpr (sizeof(CT) == 2)
                    C[(size_t)(gm + r) * N + gn] = (CT)__float2bfloat16(v);
                else
                    C[(size_t)(gm + r) * N + gn] = (CT)v;
            }
        }
}

// ---------------------------------------------------------------------------
// RoPE + RMSNorm in place on bf16 qkv (fp32 cos/sin/weights).
// ---------------------------------------------------------------------------
__global__ __launch_bounds__(256) void rope_norm(
    __hip_bfloat16* __restrict__ qkv,
    const float* __restrict__ cosb,
    const float* __restrict__ sinb,
    const float* __restrict__ qw,
    const float* __restrict__ kw)
{
    int wid  = blockIdx.x * 4 + (threadIdx.x >> 6);
    int lane = threadIdx.x & 63;
    int token = wid / 40;
    int idx   = wid % 40;
    int s = token & 2047;

    int off;
    const float* w;
    if (idx < 32) { off = (idx >> 2) * 768 + (idx & 3) * 128; w = qw; }
    else          { off = (idx - 32) * 768 + 512;             w = kw; }

    __hip_bfloat16* p = qkv + (size_t)token * 6144 + off;
    int d = lane;
    float x1 = __bfloat162float(p[d]);
    float x2 = __bfloat162float(p[d + 64]);
    float c1 = cosb[s * 128 + d], c2 = cosb[s * 128 + d + 64];
    float s1 = sinb[s * 128 + d], s2 = sinb[s * 128 + d + 64];
    float y1 = x1 * c1 - x2 * s1;
    float y2 = x2 * c2 + x1 * s2;

    float ss = y1 * y1 + y2 * y2;
#pragma unroll
    for (int m = 1; m < 64; m <<= 1) ss += __shfl_xor(ss, m, 64);
    float r = rsqrtf(ss * (1.0f / 128.0f) + 1e-5f);

    p[d]      = __float2bfloat16(y1 * r * w[d]);
    p[d + 64] = __float2bfloat16(y2 * r * w[d + 64]);
}

// ---------------------------------------------------------------------------
// V transpose: qkv V-slices -> Vt[b][kvh][d=128][s=2048] (bf16).
// Block = (b, kvh, 64-token tile). LDS-staged transpose.
// ---------------------------------------------------------------------------
__global__ __launch_bounds__(256) void vtrans(
    const __hip_bfloat16* __restrict__ qkv, __hip_bfloat16* __restrict__ Vt)
{
    __shared__ alignas(16) short lT[64 * 136];

    const int bid   = blockIdx.x;      // 512 = b(2) * kvh(8) * stile(32)
    const int stile = bid & 31;
    const int kvh   = (bid >> 5) & 7;
    const int b     = bid >> 8;
    const int tid   = threadIdx.x;
    const size_t voff = (size_t)kvh * 768 + 640;
    const short* qkvs = (const short*)qkv;

#pragma unroll
    for (int i = 0; i < 4; i++) {
        int chunk = tid + i * 256;         // 1024 = 64 tok x 16 chunks
        int t  = chunk >> 4;
        int dc = chunk & 15;
        size_t tok = (size_t)(b * 2048 + stile * 64 + t);
        *(short8*)(&lT[t * 136 + dc * 8]) =
            *(const short8*)(qkvs + tok * 6144 + voff + dc * 8);
    }
    __syncthreads();

    int d  = tid >> 1;
    int kh = (tid & 1) * 32;
    short* out = (short*)Vt + ((size_t)((b * 8 + kvh) * 128 + d)) * 2048
               + stile * 64 + kh;
#pragma unroll
    for (int jb = 0; jb < 4; jb++) {
        short8 s;
#pragma unroll
        for (int j = 0; j < 8; j++) s[j] = lT[(kh + jb * 8 + j) * 136 + d];
        *(short8*)(out + jb * 8) = s;
    }
}

// ---------------------------------------------------------------------------
// Flash attention (GQA, full softmax). Block = (b, h, 64 q-rows), 4 waves.
// K and Vt tiles staged via global_load_lds into unpadded LDS; all fragment
// reads are ds_read_b128. P round-trips per-wave LDS (C->A layout).
// ---------------------------------------------------------------------------
__global__ __launch_bounds__(256) void attn_kernel(
    const __hip_bfloat16* __restrict__ qkv,
    const __hip_bfloat16* __restrict__ Vt,
    __hip_bfloat16* __restrict__ attn_out)
{
    __shared__ alignas(16) short lK[64 * 128];    // K tile: key-major
    __shared__ alignas(16) short lVt[128 * 64];   // V tile: dim-major
    __shared__ alignas(16) short lP[4][16 * 72];

    const int bid  = blockIdx.x;            // 2048 = b(2) * h(32) * qt(32)
    const int qt   = bid & 31;
    const int h    = (bid >> 5) & 31;
    const int b    = bid >> 10;
    const int kvh  = h >> 2;
    const int wave = threadIdx.x >> 6;
    const int lane = threadIdx.x & 63;
    const int quad = lane >> 4;
    const int l16  = lane & 15;

    const size_t qoff = (size_t)kvh * 768 + (size_t)(h & 3) * 128;
    const size_t koff = (size_t)kvh * 768 + 512;
    const short* qkvs = (const short*)qkv;
    const short* Vts  = (const short*)Vt + ((size_t)(b * 8 + kvh) * 128) * 2048;

    // Q fragments: A[m=l16][k = kk*32 + quad*8 + j]
    const int qrow = qt * 64 + wave * 16 + l16;
    const size_t qtok = (size_t)(b * 2048 + qrow);
    short8 qf[4];
#pragma unroll
    for (int kk = 0; kk < 4; kk++)
        qf[kk] = *(const short8*)(qkvs + qtok * 6144 + qoff + kk * 32 + quad * 8);

    floatx4 o[8];
#pragma unroll
    for (int n = 0; n < 8; n++) o[n] = (floatx4)0.0f;
    float mrow[4], lrow[4];
#pragma unroll
    for (int r = 0; r < 4; r++) { mrow[r] = -3.0e4f; lrow[r] = 0.0f; }

    const float scale = 0.08838834764831845f;  // 1/sqrt(128)

    // staging lane coords
    const int k_key = lane >> 4;            // 0..3   (key within 4-key chunk)
    const int k_col = (lane & 15) * 8;      // elem   (16B per lane)
    const int v_row = lane >> 3;            // 0..7   (dim within 8-dim chunk)
    const int v_col = (lane & 7) * 8;       // elem

    for (int kt = 0; kt < 32; kt++) {
        __syncthreads();
#pragma unroll
        for (int i = 0; i < 4; i++) {
            int c = wave * 4 + i;           // chunk 0..15
            // lK chunk: 4 keys x 256B
            size_t tok = (size_t)(b * 2048 + kt * 64 + c * 4 + k_key);
            GLDS(qkvs + tok * 6144 + koff + k_col, &lK[c * 512]);
            // lVt chunk: 8 dims x 128B
            int d = c * 8 + v_row;
            GLDS(Vts + (size_t)d * 2048 + kt * 64 + v_col, &lVt[c * 512]);
        }
        __syncthreads();

        // S = Q K^T  (16 q-rows x 64 keys)
        floatx4 sc[4];
#pragma unroll
        for (int n = 0; n < 4; n++) sc[n] = (floatx4)0.0f;
#pragma unroll
        for (int kk = 0; kk < 4; kk++) {
#pragma unroll
            for (int n = 0; n < 4; n++) {
                short8 bfr = *(const short8*)(&lK[(n * 16 + l16) * 128 + kk * 32 + quad * 8]);
                sc[n] = __builtin_amdgcn_mfma_f32_16x16x32_bf16(qf[kk], bfr, sc[n], 0, 0, 0);
            }
        }

        // online softmax; row r of this quad = quad*4 + r
        float mnew[4], alpha[4];
#pragma unroll
        for (int r = 0; r < 4; r++) {
            float mx = fmaxf(fmaxf(sc[0][r], sc[1][r]), fmaxf(sc[2][r], sc[3][r])) * scale;
#pragma unroll
            for (int m = 1; m < 16; m <<= 1) mx = fmaxf(mx, __shfl_xor(mx, m, 64));
            float mn = fmaxf(mrow[r], mx);
            alpha[r] = __expf(mrow[r] - mn);
            mnew[r]  = mn;
        }
#pragma unroll
        for (int n = 0; n < 4; n++)
#pragma unroll
            for (int r = 0; r < 4; r++) {
                float p = __expf(sc[n][r] * scale - mnew[r]);
                sc[n][r] = p;
                lP[wave][(quad * 4 + r) * 72 + n * 16 + l16] = bf16bits(p);
            }
#pragma unroll
        for (int r = 0; r < 4; r++) {
            float sm = sc[0][r] + sc[1][r] + sc[2][r] + sc[3][r];
#pragma unroll
            for (int m = 1; m < 16; m <<= 1) sm += __shfl_xor(sm, m, 64);
            lrow[r] = lrow[r] * alpha[r] + sm;
            mrow[r] = mnew[r];
        }
#pragma unroll
        for (int n = 0; n < 8; n++)
#pragma unroll
            for (int r = 0; r < 4; r++) o[n][r] *= alpha[r];

        __syncthreads();   // fence lP stores -> vector loads

        // O += P * V : A=P[m=q][k=key], B=Vt[k=key][n=dim]
#pragma unroll
        for (int kk2 = 0; kk2 < 2; kk2++) {
            short8 pf = *(const short8*)(&lP[wave][l16 * 72 + kk2 * 32 + quad * 8]);
#pragma unroll
            for (int n = 0; n < 8; n++) {
                short8 vf = *(const short8*)(&lVt[(n * 16 + l16) * 64 + kk2 * 32 + quad * 8]);
                o[n] = __builtin_amdgcn_mfma_f32_16x16x32_bf16(pf, vf, o[n], 0, 0, 0);
            }
        }
    }

#pragma unroll
    for (int n = 0; n < 8; n++)
#pragma unroll
        for (int r = 0; r < 4; r++) {
            int row = qt * 64 + wave * 16 + quad * 4 + r;
            size_t tok = (size_t)(b * 2048 + row);
            attn_out[tok * 4096 + h * 128 + n * 16 + l16] =
                __float2bfloat16(o[n][r] / lrow[r]);
        }
}

// ---------------------------------------------------------------------------
extern "C" void kernel_launch(void* const* d_in, const int* in_sizes, int n_in,
                              void* d_out, int out_size, void* d_ws, size_t ws_size,
                              hipStream_t stream) {
    const float* hidden = (const float*)d_in[0];
    const float* cosb   = (const float*)d_in[1];
    const float* sinb   = (const float*)d_in[2];
    const float* w_qkv  = (const float*)d_in[3];
    const float* w_o    = (const float*)d_in[4];
    const float* qw     = (const float*)d_in[5];
    const float* kw     = (const float*)d_in[6];

    char* ws = (char*)d_ws;
    __hip_bfloat16* qkv    = (__hip_bfloat16*)ws;                     // 50.33 MB
    __hip_bfloat16* attn_o = (__hip_bfloat16*)(ws + 50331648);        // 33.55 MB
    // optional bf16 copies (fast path)
    __hip_bfloat16* hb  = (__hip_bfloat16*)(ws + 83886080);           // 33.55 MB
    __hip_bfloat16* wb1 = (__hip_bfloat16*)(ws + 117440512);          // 50.33 MB
    __hip_bfloat16* wb2 = (__hip_bfloat16*)(ws + 167772160);          // 33.55 MB
    const size_t WS_FAST = 201326592;                                  // 192 MiB

    // Vt scratch lives in d_out (8.4 MB; fully overwritten by final GEMM)
    __hip_bfloat16* Vt = (__hip_bfloat16*)d_out;
    float* outp        = (float*)d_out;

    const bool fast = (ws_size >= WS_FAST);

    if (fast) {
        cvt_bf16<<<16777216 / 8 / 256, 256, 0, stream>>>(hidden, hb);
        cvt_bf16<<<25165824 / 8 / 256, 256, 0, stream>>>(w_qkv, wb1);
        cvt_bf16<<<16777216 / 8 / 256, 256, 0, stream>>>(w_o, wb2);
        dim3 g1(32, 48);
        gemm_bt_fast<__hip_bfloat16><<<g1, 256, 0, stream>>>(hb, wb1, qkv, 4096, 6144, 4096);
    } else {
        dim3 g1(32, 48);
        gemm_bt_slow<true, __hip_bfloat16><<<g1, 256, 0, stream>>>(hidden, w_qkv, qkv, 4096, 6144, 4096);
    }

    rope_norm<<<40960, 256, 0, stream>>>(qkv, cosb, sinb, qw, kw);

    vtrans<<<512, 256, 0, stream>>>(qkv, Vt);

    attn_kernel<<<2048, 256, 0, stream>>>(qkv, Vt, attn_o);

    dim3 g2(32, 32);
    if (fast) {
        gemm_bt_fast<float><<<g2, 256, 0, stream>>>(attn_o, wb2, outp, 4096, 4096, 4096);
    } else {
        gemm_bt_slow<false, float><<<g2, 256, 0, stream>>>(attn_o, w_o, outp, 4096, 4096, 4096);
    }
}

// Round 6
// 915.920 us; speedup vs baseline: 1.9544x; 1.4002x over previous
//
#include <hip/hip_runtime.h>
#include <hip/hip_bf16.h>

typedef __attribute__((ext_vector_type(8))) short short8;
typedef __attribute__((ext_vector_type(4))) float floatx4;

static __device__ __forceinline__ short bf16bits(float f) {
    __hip_bfloat16 h = __float2bfloat16(f);
    return __builtin_bit_cast(short, h);
}

#define GLDS(g, l) __builtin_amdgcn_global_load_lds( \
    (const __attribute__((address_space(1))) void*)(g), \
    (__attribute__((address_space(3))) void*)(l), 16, 0, 0)

// ---------------------------------------------------------------------------
// fp32 -> bf16 bulk convert. Thread i handles 8 elems.
// ---------------------------------------------------------------------------
__global__ __launch_bounds__(256) void cvt_bf16(
    const float* __restrict__ src, __hip_bfloat16* __restrict__ dst)
{
    size_t i = ((size_t)blockIdx.x * 256 + threadIdx.x) * 8;
    floatx4 f0 = *(const floatx4*)(src + i);
    floatx4 f1 = *(const floatx4*)(src + i + 4);
    short8 s;
#pragma unroll
    for (int j = 0; j < 4; j++) { s[j] = bf16bits(f0[j]); s[j + 4] = bf16bits(f1[j]); }
    *(short8*)((short*)dst + i) = s;
}

// ---------------------------------------------------------------------------
// FAST GEMM, XOR-swizzled LDS: C[M,N] = A[M,K] * W[N,K]^T, bf16 in, fp32 acc.
// 128x128 tile, BK=64. Rows are 64 shorts = 8 x 16B blocks; block j of row r
// holds logical block j ^ (r&7) (swizzled at GLDS staging via source addr).
// Fragment reads: physical block = (kk2*4+quad) ^ (l16&7) -> 2-way = free.
// ---------------------------------------------------------------------------
template<typename CT>
__global__ __launch_bounds__(256) void gemm_bt_fast(
    const __hip_bfloat16* __restrict__ A,
    const __hip_bfloat16* __restrict__ W,
    CT* __restrict__ C, int M, int N, int K)
{
    __shared__ alignas(16) short lA[128 * 64];
    __shared__ alignas(16) short lB[128 * 64];

    const int tid  = threadIdx.x;
    const int wave = tid >> 6;
    const int lane = tid & 63;
    const int quad = lane >> 4;
    const int l16  = lane & 15;

    const int m0 = blockIdx.x * 128;
    const int n0 = blockIdx.y * 128;
    const int wm = (wave & 1) * 64;
    const int wn = (wave >> 1) * 64;

    const int srow = lane >> 3;                    // 0..7 row within chunk
    const int sblk = (lane & 7) ^ srow;            // swizzled source block
    const int scol = sblk * 8;

    const short* Ag = (const short*)A;
    const short* Wg = (const short*)W;

    floatx4 acc[4][4];
#pragma unroll
    for (int i = 0; i < 4; i++)
#pragma unroll
        for (int j = 0; j < 4; j++) acc[i][j] = (floatx4)0.0f;

    for (int k0 = 0; k0 < K; k0 += 64) {
        __syncthreads();
#pragma unroll
        for (int i = 0; i < 4; i++) {
            int c   = wave * 4 + i;            // chunk 0..15 = 8 rows x 1KB
            int row = c * 8 + srow;
            GLDS(Ag + (size_t)(m0 + row) * K + k0 + scol, &lA[c * 512]);
            GLDS(Wg + (size_t)(n0 + row) * K + k0 + scol, &lB[c * 512]);
        }
        __syncthreads();
#pragma unroll
        for (int kk2 = 0; kk2 < 2; kk2++) {
            const int pb = ((kk2 * 4 + quad) ^ (l16 & 7)) * 8;
            short8 af[4], bf[4];
#pragma unroll
            for (int i = 0; i < 4; i++)
                af[i] = *(const short8*)(&lA[(wm + i * 16 + l16) * 64 + pb]);
#pragma unroll
            for (int j = 0; j < 4; j++)
                bf[j] = *(const short8*)(&lB[(wn + j * 16 + l16) * 64 + pb]);
#pragma unroll
            for (int i = 0; i < 4; i++)
#pragma unroll
                for (int j = 0; j < 4; j++)
                    acc[i][j] = __builtin_amdgcn_mfma_f32_16x16x32_bf16(
                        af[i], bf[j], acc[i][j], 0, 0, 0);
        }
    }
#pragma unroll
    for (int i = 0; i < 4; i++)
#pragma unroll
        for (int j = 0; j < 4; j++) {
            int gm = m0 + wm + i * 16 + quad * 4;
            int gn = n0 + wn + j * 16 + l16;
#pragma unroll
            for (int r = 0; r < 4; r++) {
                float v = acc[i][j][r];
                if constexpr (sizeof(CT) == 2)
                    C[(size_t)(gm + r) * N + gn] = (CT)__float2bfloat16(v);
                else
                    C[(size_t)(gm + r) * N + gn] = (CT)v;
            }
        }
}

// ---------------------------------------------------------------------------
// FALLBACK GEMM (round-4 proven) — used only if ws too small for bf16 copies.
// ---------------------------------------------------------------------------
template<bool AF32, typename CT>
__global__ __launch_bounds__(256) void gemm_bt_slow(
    const void* __restrict__ A,
    const float* __restrict__ Wf,
    CT* __restrict__ C, int M, int N, int K)
{
    __shared__ alignas(16) short lA[128 * 72];
    __shared__ alignas(16) short lB[128 * 72];

    const int tid  = threadIdx.x;
    const int wave = tid >> 6;
    const int lane = tid & 63;
    const int quad = lane >> 4;
    const int l16  = lane & 15;

    const int m0 = blockIdx.x * 128;
    const int n0 = blockIdx.y * 128;
    const int wm = (wave & 1) * 64;
    const int wn = (wave >> 1) * 64;

    floatx4 acc[4][4];
#pragma unroll
    for (int i = 0; i < 4; i++)
#pragma unroll
        for (int j = 0; j < 4; j++) acc[i][j] = (floatx4)0.0f;

    const short* Ab = (const short*)A;
    const float* Af = (const float*)A;

    for (int k0 = 0; k0 < K; k0 += 64) {
        __syncthreads();
#pragma unroll
        for (int i = 0; i < 4; i++) {
            int chunk = tid + i * 256;
            int row = chunk >> 3;
            int cc  = chunk & 7;
            if (AF32) {
                const float* src = Af + (size_t)(m0 + row) * K + k0 + cc * 8;
                floatx4 f0 = *(const floatx4*)(src);
                floatx4 f1 = *(const floatx4*)(src + 4);
                short8 s;
#pragma unroll
                for (int j = 0; j < 4; j++) { s[j] = bf16bits(f0[j]); s[j + 4] = bf16bits(f1[j]); }
                *(short8*)(&lA[row * 72 + cc * 8]) = s;
            } else {
                *(short8*)(&lA[row * 72 + cc * 8]) =
                    *(const short8*)(Ab + (size_t)(m0 + row) * K + k0 + cc * 8);
            }
            const float* src = Wf + (size_t)(n0 + row) * K + k0 + cc * 8;
            floatx4 f0 = *(const floatx4*)(src);
            floatx4 f1 = *(const floatx4*)(src + 4);
            short8 s;
#pragma unroll
            for (int j = 0; j < 4; j++) { s[j] = bf16bits(f0[j]); s[j + 4] = bf16bits(f1[j]); }
            *(short8*)(&lB[row * 72 + cc * 8]) = s;
        }
        __syncthreads();
#pragma unroll
        for (int kk = 0; kk < 64; kk += 32) {
            short8 af[4], bf[4];
#pragma unroll
            for (int i = 0; i < 4; i++)
                af[i] = *(const short8*)(&lA[(wm + i * 16 + l16) * 72 + kk + quad * 8]);
#pragma unroll
            for (int j = 0; j < 4; j++)
                bf[j] = *(const short8*)(&lB[(wn + j * 16 + l16) * 72 + kk + quad * 8]);
#pragma unroll
            for (int i = 0; i < 4; i++)
#pragma unroll
                for (int j = 0; j < 4; j++)
                    acc[i][j] = __builtin_amdgcn_mfma_f32_16x16x32_bf16(
                        af[i], bf[j], acc[i][j], 0, 0, 0);
        }
    }
#pragma unroll
    for (int i = 0; i < 4; i++)
#pragma unroll
        for (int j = 0; j < 4; j++) {
            int gm = m0 + wm + i * 16 + quad * 4;
            int gn = n0 + wn + j * 16 + l16;
#pragma unroll
            for (int r = 0; r < 4; r++) {
                float v = acc[i][j][r];
                if constexpr (sizeof(CT) == 2)
                    C[(size_t)(gm + r) * N + gn] = (CT)__float2bfloat16(v);
                else
                    C[(size_t)(gm + r) * N + gn] = (CT)v;
            }
        }
}

// ---------------------------------------------------------------------------
// RoPE + RMSNorm in place on bf16 qkv (fp32 cos/sin/weights).
// ---------------------------------------------------------------------------
__global__ __launch_bounds__(256) void rope_norm(
    __hip_bfloat16* __restrict__ qkv,
    const float* __restrict__ cosb,
    const float* __restrict__ sinb,
    const float* __restrict__ qw,
    const float* __restrict__ kw)
{
    int wid  = blockIdx.x * 4 + (threadIdx.x >> 6);
    int lane = threadIdx.x & 63;
    int token = wid / 40;
    int idx   = wid % 40;
    int s = token & 2047;

    int off;
    const float* w;
    if (idx < 32) { off = (idx >> 2) * 768 + (idx & 3) * 128; w = qw; }
    else          { off = (idx - 32) * 768 + 512;             w = kw; }

    __hip_bfloat16* p = qkv + (size_t)token * 6144 + off;
    int d = lane;
    float x1 = __bfloat162float(p[d]);
    float x2 = __bfloat162float(p[d + 64]);
    float c1 = cosb[s * 128 + d], c2 = cosb[s * 128 + d + 64];
    float s1 = sinb[s * 128 + d], s2 = sinb[s * 128 + d + 64];
    float y1 = x1 * c1 - x2 * s1;
    float y2 = x2 * c2 + x1 * s2;

    float ss = y1 * y1 + y2 * y2;
#pragma unroll
    for (int m = 1; m < 64; m <<= 1) ss += __shfl_xor(ss, m, 64);
    float r = rsqrtf(ss * (1.0f / 128.0f) + 1e-5f);

    p[d]      = __float2bfloat16(y1 * r * w[d]);
    p[d + 64] = __float2bfloat16(y2 * r * w[d + 64]);
}

// ---------------------------------------------------------------------------
// V transpose: qkv V-slices -> Vt[b][kvh][d=128][s=2048] (bf16).
// ---------------------------------------------------------------------------
__global__ __launch_bounds__(256) void vtrans(
    const __hip_bfloat16* __restrict__ qkv, __hip_bfloat16* __restrict__ Vt)
{
    __shared__ alignas(16) short lT[64 * 136];

    const int bid   = blockIdx.x;      // 512 = b(2) * kvh(8) * stile(32)
    const int stile = bid & 31;
    const int kvh   = (bid >> 5) & 7;
    const int b     = bid >> 8;
    const int tid   = threadIdx.x;
    const size_t voff = (size_t)kvh * 768 + 640;
    const short* qkvs = (const short*)qkv;

#pragma unroll
    for (int i = 0; i < 4; i++) {
        int chunk = tid + i * 256;
        int t  = chunk >> 4;
        int dc = chunk & 15;
        size_t tok = (size_t)(b * 2048 + stile * 64 + t);
        *(short8*)(&lT[t * 136 + dc * 8]) =
            *(const short8*)(qkvs + tok * 6144 + voff + dc * 8);
    }
    __syncthreads();

    int d  = tid >> 1;
    int kh = (tid & 1) * 32;
    short* out = (short*)Vt + ((size_t)((b * 8 + kvh) * 128 + d)) * 2048
               + stile * 64 + kh;
#pragma unroll
    for (int jb = 0; jb < 4; jb++) {
        short8 s;
#pragma unroll
        for (int j = 0; j < 8; j++) s[j] = lT[(kh + jb * 8 + j) * 136 + d];
        *(short8*)(out + jb * 8) = s;
    }
}

// ---------------------------------------------------------------------------
// Flash attention (GQA, full softmax). Block = (b, h, 128 q-rows), 4 waves,
// each wave 32 q-rows (2 m-tiles). XOR-swizzled LDS (conflict-free b128):
//   lK : 64 keys x 128 dims, 16 blocks/row, block j holds logical j^(r&15)
//   lVt: 128 dims x 64 toks,  8 blocks/row, block j holds logical j^(r&7)
//   lP : per-wave 32 x 64,    8 blocks/row, same swizzle
// ---------------------------------------------------------------------------
__global__ __launch_bounds__(256, 2) void attn_kernel(
    const __hip_bfloat16* __restrict__ qkv,
    const __hip_bfloat16* __restrict__ Vt,
    __hip_bfloat16* __restrict__ attn_out)
{
    __shared__ alignas(16) short lK[64 * 128];
    __shared__ alignas(16) short lVt[128 * 64];
    __shared__ alignas(16) short lP[4][32 * 64];

    const int bid  = blockIdx.x;            // 1024 = b(2) * h(32) * qt(16)
    const int qt   = bid & 15;
    const int h    = (bid >> 4) & 31;
    const int b    = bid >> 9;
    const int kvh  = h >> 2;
    const int wave = threadIdx.x >> 6;
    const int lane = threadIdx.x & 63;
    const int quad = lane >> 4;
    const int l16  = lane & 15;

    const size_t qoff = (size_t)kvh * 768 + (size_t)(h & 3) * 128;
    const size_t koff = (size_t)kvh * 768 + 512;
    const short* qkvs = (const short*)qkv;
    const short* Vts  = (const short*)Vt + ((size_t)(b * 8 + kvh) * 128) * 2048;

    // Q fragments: 2 m-tiles x 4 k-steps. A[m=l16][k = kk*32 + quad*8 + j]
    short8 qf[2][4];
#pragma unroll
    for (int t = 0; t < 2; t++) {
        const int qrow = qt * 128 + wave * 32 + t * 16 + l16;
        const size_t qtok = (size_t)(b * 2048 + qrow);
#pragma unroll
        for (int kk = 0; kk < 4; kk++)
            qf[t][kk] = *(const short8*)(qkvs + qtok * 6144 + qoff + kk * 32 + quad * 8);
    }

    floatx4 o[2][8];
#pragma unroll
    for (int t = 0; t < 2; t++)
#pragma unroll
        for (int n = 0; n < 8; n++) o[t][n] = (floatx4)0.0f;
    float mrow[2][4], lrow[2][4];
#pragma unroll
    for (int t = 0; t < 2; t++)
#pragma unroll
        for (int r = 0; r < 4; r++) { mrow[t][r] = -3.0e4f; lrow[t][r] = 0.0f; }

    const float scale = 0.08838834764831845f;  // 1/sqrt(128)

    // staging lane coords (swizzled source blocks)
    const int k_row = lane >> 4;                       // 0..3 key in chunk
    const int v_row = lane >> 3;                       // 0..7 dim in chunk
    const int v_blk = (lane & 7) ^ v_row;              // lVt swizzle (row&7 = v_row)

    for (int kt = 0; kt < 32; kt++) {
        __syncthreads();
#pragma unroll
        for (int i = 0; i < 4; i++) {
            int c = wave * 4 + i;           // chunk 0..15
            // lK chunk: 4 keys x 256B ; source block = j ^ ((4c+k_row)&15)
            int k_blk = (lane & 15) ^ ((c * 4 + k_row) & 15);
            size_t tok = (size_t)(b * 2048 + kt * 64 + c * 4 + k_row);
            GLDS(qkvs + tok * 6144 + koff + k_blk * 8, &lK[c * 512]);
            // lVt chunk: 8 dims x 128B ; source block = j ^ v_row
            int d = c * 8 + v_row;
            GLDS(Vts + (size_t)d * 2048 + kt * 64 + v_blk * 8, &lVt[c * 512]);
        }
        __syncthreads();

        // S = Q K^T  (2 x 16 q-rows x 64 keys)
        floatx4 sc[2][4];
#pragma unroll
        for (int t = 0; t < 2; t++)
#pragma unroll
            for (int n = 0; n < 4; n++) sc[t][n] = (floatx4)0.0f;
#pragma unroll
        for (int kk = 0; kk < 4; kk++) {
#pragma unroll
            for (int n = 0; n < 4; n++) {
                short8 bfr = *(const short8*)(
                    &lK[(n * 16 + l16) * 128 + (((kk * 4 + quad) ^ l16)) * 8]);
                sc[0][n] = __builtin_amdgcn_mfma_f32_16x16x32_bf16(qf[0][kk], bfr, sc[0][n], 0, 0, 0);
                sc[1][n] = __builtin_amdgcn_mfma_f32_16x16x32_bf16(qf[1][kk], bfr, sc[1][n], 0, 0, 0);
            }
        }

        // online softmax per (t, r); reduce over l16 lanes
#pragma unroll
        for (int t = 0; t < 2; t++) {
            float mnew[4], alpha[4];
#pragma unroll
            for (int r = 0; r < 4; r++) {
                float mx = fmaxf(fmaxf(sc[t][0][r], sc[t][1][r]),
                                 fmaxf(sc[t][2][r], sc[t][3][r])) * scale;
#pragma unroll
                for (int m = 1; m < 16; m <<= 1) mx = fmaxf(mx, __shfl_xor(mx, m, 64));
                float mn = fmaxf(mrow[t][r], mx);
                alpha[r] = __expf(mrow[t][r] - mn);
                mnew[r]  = mn;
            }
#pragma unroll
            for (int n = 0; n < 4; n++)
#pragma unroll
                for (int r = 0; r < 4; r++) {
                    float p = __expf(sc[t][n][r] * scale - mnew[r]);
                    sc[t][n][r] = p;
                    int row = t * 16 + quad * 4 + r;
                    int pblk = (n * 2 + (l16 >> 3)) ^ (row & 7);
                    lP[wave][row * 64 + pblk * 8 + (l16 & 7)] = bf16bits(p);
                }
#pragma unroll
            for (int r = 0; r < 4; r++) {
                float sm = sc[t][0][r] + sc[t][1][r] + sc[t][2][r] + sc[t][3][r];
#pragma unroll
                for (int m = 1; m < 16; m <<= 1) sm += __shfl_xor(sm, m, 64);
                lrow[t][r] = lrow[t][r] * alpha[r] + sm;
                mrow[t][r] = mnew[r];
            }
#pragma unroll
            for (int n = 0; n < 8; n++)
#pragma unroll
                for (int r = 0; r < 4; r++) o[t][n][r] *= alpha[r];
        }

        __threadfence_block();   // order lP scalar-stores -> b128 loads (wave-local)

        // O += P * V
#pragma unroll
        for (int kk2 = 0; kk2 < 2; kk2++) {
            const int pb = ((kk2 * 4 + quad) ^ (l16 & 7)) * 8;
            short8 pf0 = *(const short8*)(&lP[wave][(l16)      * 64 + pb]);
            short8 pf1 = *(const short8*)(&lP[wave][(16 + l16) * 64 + pb]);
#pragma unroll
            for (int n = 0; n < 8; n++) {
                short8 vf = *(const short8*)(&lVt[(n * 16 + l16) * 64 + pb]);
                o[0][n] = __builtin_amdgcn_mfma_f32_16x16x32_bf16(pf0, vf, o[0][n], 0, 0, 0);
                o[1][n] = __builtin_amdgcn_mfma_f32_16x16x32_bf16(pf1, vf, o[1][n], 0, 0, 0);
            }
        }
    }

#pragma unroll
    for (int t = 0; t < 2; t++)
#pragma unroll
        for (int n = 0; n < 8; n++)
#pragma unroll
            for (int r = 0; r < 4; r++) {
                int row = qt * 128 + wave * 32 + t * 16 + quad * 4 + r;
                size_t tok = (size_t)(b * 2048 + row);
                attn_out[tok * 4096 + h * 128 + n * 16 + l16] =
                    __float2bfloat16(o[t][n][r] / lrow[t][r]);
            }
}

// ---------------------------------------------------------------------------
extern "C" void kernel_launch(void* const* d_in, const int* in_sizes, int n_in,
                              void* d_out, int out_size, void* d_ws, size_t ws_size,
                              hipStream_t stream) {
    const float* hidden = (const float*)d_in[0];
    const float* cosb   = (const float*)d_in[1];
    const float* sinb   = (const float*)d_in[2];
    const float* w_qkv  = (const float*)d_in[3];
    const float* w_o    = (const float*)d_in[4];
    const float* qw     = (const float*)d_in[5];
    const float* kw     = (const float*)d_in[6];

    char* ws = (char*)d_ws;
    __hip_bfloat16* qkv    = (__hip_bfloat16*)ws;                     // 50.33 MB
    __hip_bfloat16* attn_o = (__hip_bfloat16*)(ws + 50331648);        // 33.55 MB
    __hip_bfloat16* hb  = (__hip_bfloat16*)(ws + 83886080);           // 33.55 MB
    __hip_bfloat16* wb1 = (__hip_bfloat16*)(ws + 117440512);          // 50.33 MB
    __hip_bfloat16* wb2 = (__hip_bfloat16*)(ws + 167772160);          // 33.55 MB
    const size_t WS_FAST = 201326592;                                  // 192 MiB

    __hip_bfloat16* Vt = (__hip_bfloat16*)d_out;   // 8.4 MB scratch, dead before gemm2
    float* outp        = (float*)d_out;

    const bool fast = (ws_size >= WS_FAST);

    if (fast) {
        cvt_bf16<<<16777216 / 8 / 256, 256, 0, stream>>>(hidden, hb);
        cvt_bf16<<<25165824 / 8 / 256, 256, 0, stream>>>(w_qkv, wb1);
        cvt_bf16<<<16777216 / 8 / 256, 256, 0, stream>>>(w_o, wb2);
        dim3 g1(32, 48);
        gemm_bt_fast<__hip_bfloat16><<<g1, 256, 0, stream>>>(hb, wb1, qkv, 4096, 6144, 4096);
    } else {
        dim3 g1(32, 48);
        gemm_bt_slow<true, __hip_bfloat16><<<g1, 256, 0, stream>>>(hidden, w_qkv, qkv, 4096, 6144, 4096);
    }

    rope_norm<<<40960, 256, 0, stream>>>(qkv, cosb, sinb, qw, kw);

    vtrans<<<512, 256, 0, stream>>>(qkv, Vt);

    attn_kernel<<<1024, 256, 0, stream>>>(qkv, Vt, attn_o);

    dim3 g2(32, 32);
    if (fast) {
        gemm_bt_fast<float><<<g2, 256, 0, stream>>>(attn_o, wb2, outp, 4096, 4096, 4096);
    } else {
        gemm_bt_slow<false, float><<<g2, 256, 0, stream>>>(attn_o, w_o, outp, 4096, 4096, 4096);
    }
}